// Round 1
// baseline (394.546 us; speedup 1.0000x reference)
//
#include <hip/hip_runtime.h>

// TopK_36653250904599: x [16,256,128,128] f32 -> l2-normalize over HW=16384,
// top-16 values [B,C,16] + (h,w) coords [B,C,16,2].
// Output buffer = float32 throughout (coords stored as float-valued ints).
//
// Strategy: one block per (b,c) row. Single coalesced float4 pass computes
// sum(x^2) and filters candidates > T=2.5 into LDS (expected ~102/row for
// N(0,1) data; block-uniform bisection fallback rescans if count outside
// [16, CAP] -- never fires on this input). Rank candidates by all-pairs
// comparison on (normalized-value bits, ~idx) packed u64, matching
// jax.lax.top_k ordering (value desc, index asc on fp32 ties of the
// *normalized* values).

#define KSEL 16
#define HW   16384
#define WDIM 128
#define CAP  1024
#define T0   2.5f
#define NROWS 4096
#define VALS_TOTAL (NROWS * KSEL)   // 65536 floats, then coords

__device__ __forceinline__ void push_cand(unsigned long long* cand,
                                          unsigned* cnt, float v, int idx) {
    unsigned u = __float_as_uint(v);
    // order-preserving bijection float -> uint
    unsigned m = u ^ (((unsigned)((int)u >> 31)) | 0x80000000u);
    unsigned long long p =
        ((unsigned long long)m << 32) | (unsigned)(16383 - idx);
    unsigned slot = atomicAdd(cnt, 1u);
    if (slot < CAP) cand[slot] = p;
}

__global__ __launch_bounds__(256) void topk_rows(const float* __restrict__ x,
                                                 float* __restrict__ out) {
    const int row = blockIdx.x;
    const int t   = threadIdx.x;

    __shared__ unsigned long long s_cand[CAP];
    __shared__ unsigned s_cnt;
    __shared__ float s_part[4];
    __shared__ float s_scale;

    if (t == 0) s_cnt = 0;
    __syncthreads();

    const float4* rowp = (const float4*)(x + (size_t)row * HW);

    float T = T0;
    float sumsq = 0.0f;
    #pragma unroll
    for (int k = 0; k < 16; ++k) {
        float4 f = rowp[k * 256 + t];
        int base = k * 1024 + t * 4;
        sumsq = fmaf(f.x, f.x, sumsq);
        sumsq = fmaf(f.y, f.y, sumsq);
        sumsq = fmaf(f.z, f.z, sumsq);
        sumsq = fmaf(f.w, f.w, sumsq);
        if (f.x > T) push_cand(s_cand, &s_cnt, f.x, base + 0);
        if (f.y > T) push_cand(s_cand, &s_cnt, f.y, base + 1);
        if (f.z > T) push_cand(s_cand, &s_cnt, f.z, base + 2);
        if (f.w > T) push_cand(s_cand, &s_cnt, f.w, base + 3);
    }

    // block reduce sumsq
    #pragma unroll
    for (int off = 32; off > 0; off >>= 1)
        sumsq += __shfl_down(sumsq, off, 64);
    if ((t & 63) == 0) s_part[t >> 6] = sumsq;
    __syncthreads();   // pushes + partials complete
    if (t == 0) {
        float tot = s_part[0] + s_part[1] + s_part[2] + s_part[3];
        s_scale = 1.0f / sqrtf(fmaxf(tot, 1e-12f));
    }
    unsigned cnt = s_cnt;  // final after the sync above; block-uniform

    // Robustness fallback: bisect T until 16 <= cnt <= CAP. Never fires for
    // N(0,1) rows (P ~ 1e-25), costs one uniform branch.
    float lo = -3.0e38f, hi = 3.0e38f;
    for (int it = 0; it < 24 && (cnt < KSEL || cnt > CAP); ++it) {
        if (cnt < KSEL) { hi = T; T = (lo < -1.0e38f) ? T - 1.0f : 0.5f * (lo + T); }
        else            { lo = T; T = (hi >  1.0e38f) ? T + 1.0f : 0.5f * (T + hi); }
        __syncthreads();
        if (t == 0) s_cnt = 0;
        __syncthreads();
        for (int k = 0; k < 16; ++k) {
            float4 f = rowp[k * 256 + t];
            int base = k * 1024 + t * 4;
            if (f.x > T) push_cand(s_cand, &s_cnt, f.x, base + 0);
            if (f.y > T) push_cand(s_cand, &s_cnt, f.y, base + 1);
            if (f.z > T) push_cand(s_cand, &s_cnt, f.z, base + 2);
            if (f.w > T) push_cand(s_cand, &s_cnt, f.w, base + 3);
        }
        __syncthreads();
        cnt = s_cnt;
    }
    if (cnt > CAP) cnt = CAP;
    __syncthreads();           // s_scale visible to all
    const float scale = s_scale;

    // Re-pack candidates with the *normalized, fp32-rounded* value so the
    // ordering (incl. ties created by rounding) matches the reference.
    for (unsigned i = t; i < cnt; i += 256) {
        unsigned long long p = s_cand[i];
        unsigned m = (unsigned)(p >> 32);
        unsigned u = (m & 0x80000000u) ? (m ^ 0x80000000u) : ~m;
        float vn = __uint_as_float(u) * scale;
        unsigned u2 = __float_as_uint(vn);
        unsigned m2 = u2 ^ (((unsigned)((int)u2 >> 31)) | 0x80000000u);
        s_cand[i] = ((unsigned long long)m2 << 32) | (p & 0xFFFFFFFFull);
    }
    __syncthreads();

    // All-pairs rank; ranks are unique (idx in low bits), so each of the
    // top-16 output slots is written exactly once.
    for (unsigned i = t; i < cnt; i += 256) {
        unsigned long long p = s_cand[i];
        int rank = 0;
        for (unsigned j = 0; j < cnt; ++j) rank += (s_cand[j] > p) ? 1 : 0;
        if (rank < KSEL) {
            unsigned m = (unsigned)(p >> 32);
            unsigned u = (m & 0x80000000u) ? (m ^ 0x80000000u) : ~m;
            float vn = __uint_as_float(u);
            int idx = 16383 - (int)(unsigned)(p & 0xFFFFFFFFull);
            out[row * KSEL + rank] = vn;
            float* coor = out + VALS_TOTAL + ((size_t)row * KSEL + rank) * 2;
            coor[0] = (float)(idx >> 7);          // h = idx / 128
            coor[1] = (float)(idx & (WDIM - 1));  // w = idx % 128
        }
    }
}

extern "C" void kernel_launch(void* const* d_in, const int* in_sizes, int n_in,
                              void* d_out, int out_size, void* d_ws, size_t ws_size,
                              hipStream_t stream) {
    const float* x = (const float*)d_in[0];
    float* out = (float*)d_out;
    topk_rows<<<NROWS, 256, 0, stream>>>(x, out);
}

// Round 2
// 361.286 us; speedup vs baseline: 1.0921x; 1.0921x over previous
//
#include <hip/hip_runtime.h>

// TopK_36653250904599: x [16,256,128,128] f32 -> l2-normalize over HW=16384,
// top-16 values [B,C,16] + (h,w) coords [B,C,16,2] (coords stored as floats;
// harness reads whole tuple buffer as float32).
//
// R2: register-stage the whole row slice per thread (16 float4 = 64 VGPRs)
// so the 16 global loads issue as one unbroken batch (max outstanding loads,
// no divergent atomics between them). Sumsq = branchless FMA chain over regs.
// Candidate filter (> T0=2.5, ~102/row expected for N(0,1)) runs from regs
// via wave-ballot compaction: one scalar branch per component (taken ~33%),
// one leader atomicAdd per nonzero ballot. Bisection fallback (never fires
// for this input) rescans REGISTERS -- no second HBM pass.
// Final: repack with normalized fp32-rounded value, all-pairs rank (matches
// jax.lax.top_k ordering incl. rounding-induced ties, idx-asc tiebreak).

#define KSEL 16
#define HW   16384
#define WDIM 128
#define CAP  1024
#define T0   2.5f
#define NROWS 4096
#define VALS_TOTAL (NROWS * KSEL)   // 65536 value floats, then coords

__global__ __launch_bounds__(256) void topk_rows(const float* __restrict__ x,
                                                 float* __restrict__ out) {
    const int row  = blockIdx.x;
    const int t    = threadIdx.x;
    const int lane = t & 63;

    __shared__ unsigned long long s_cand[CAP];
    __shared__ unsigned s_cnt;
    __shared__ float s_part[4];
    __shared__ float s_scale;

    const float4* rowp = (const float4*)(x + (size_t)row * HW);

    // ---- one unbroken batch of 16 independent 16B loads ----
    float4 buf[16];
    #pragma unroll
    for (int k = 0; k < 16; ++k) buf[k] = rowp[k * 256 + t];

    // ---- branchless sumsq over registers ----
    float sumsq = 0.0f;
    #pragma unroll
    for (int k = 0; k < 16; ++k) {
        sumsq = fmaf(buf[k].x, buf[k].x, sumsq);
        sumsq = fmaf(buf[k].y, buf[k].y, sumsq);
        sumsq = fmaf(buf[k].z, buf[k].z, sumsq);
        sumsq = fmaf(buf[k].w, buf[k].w, sumsq);
    }
    #pragma unroll
    for (int off = 32; off > 0; off >>= 1)
        sumsq += __shfl_down(sumsq, off, 64);
    if (lane == 0) s_part[t >> 6] = sumsq;
    __syncthreads();
    if (t == 0) {
        float tot = s_part[0] + s_part[1] + s_part[2] + s_part[3];
        s_scale = 1.0f / sqrtf(fmaxf(tot, 1e-12f));
    }

    // ---- ballot compaction from registers (+ uniform bisection fallback) ----
    float T = T0, lo = -3.0e38f, hi = 3.0e38f;
    unsigned cnt = 0;
    for (int attempt = 0; attempt < 25; ++attempt) {
        __syncthreads();
        if (t == 0) s_cnt = 0;
        __syncthreads();
        #pragma unroll
        for (int k = 0; k < 16; ++k) {
            #pragma unroll
            for (int c = 0; c < 4; ++c) {
                float v = (c == 0) ? buf[k].x : (c == 1) ? buf[k].y
                        : (c == 2) ? buf[k].z : buf[k].w;
                bool p = v > T;
                unsigned long long m = __ballot(p);
                if (m) {  // wave-uniform scalar branch, usually not taken
                    int nb  = __popcll(m);
                    int ldr = (int)__builtin_ctzll(m);
                    unsigned base = 0;
                    if (lane == ldr) base = atomicAdd(&s_cnt, (unsigned)nb);
                    base = (unsigned)__shfl((int)base, ldr, 64);
                    if (p) {
                        unsigned pos = base +
                            (unsigned)__popcll(m & ((1ull << lane) - 1ull));
                        if (pos < CAP) {
                            unsigned u  = __float_as_uint(v);
                            unsigned mm = u ^ (((unsigned)((int)u >> 31)) | 0x80000000u);
                            int idx = k * 1024 + t * 4 + c;
                            s_cand[pos] = ((unsigned long long)mm << 32) |
                                          (unsigned)(16383 - idx);
                        }
                    }
                }
            }
        }
        __syncthreads();
        cnt = s_cnt;
        if (cnt >= KSEL && cnt <= CAP) break;
        if (cnt < KSEL) { hi = T; T = (lo < -1.0e38f) ? T - 1.0f : 0.5f * (lo + T); }
        else            { lo = T; T = (hi >  1.0e38f) ? T + 1.0f : 0.5f * (T + hi); }
    }
    if (cnt > CAP) cnt = CAP;
    const float scale = s_scale;   // ordered by the barriers in the loop above

    // ---- repack with normalized fp32-rounded value (rounding can create
    //      ties; idx tiebreak in low bits matches jax.lax.top_k) ----
    for (unsigned i = t; i < cnt; i += 256) {
        unsigned long long p = s_cand[i];
        unsigned m = (unsigned)(p >> 32);
        unsigned u = (m & 0x80000000u) ? (m ^ 0x80000000u) : ~m;
        float vn = __uint_as_float(u) * scale;
        unsigned u2 = __float_as_uint(vn);
        unsigned m2 = u2 ^ (((unsigned)((int)u2 >> 31)) | 0x80000000u);
        s_cand[i] = ((unsigned long long)m2 << 32) | (p & 0xFFFFFFFFull);
    }
    __syncthreads();

    // ---- all-pairs rank (ranks unique via idx tiebreak) + write ----
    for (unsigned i = t; i < cnt; i += 256) {
        unsigned long long p = s_cand[i];
        int rank = 0;
        for (unsigned j = 0; j < cnt; ++j) rank += (s_cand[j] > p) ? 1 : 0;
        if (rank < KSEL) {
            unsigned m = (unsigned)(p >> 32);
            unsigned u = (m & 0x80000000u) ? (m ^ 0x80000000u) : ~m;
            float vn = __uint_as_float(u);
            int idx = 16383 - (int)(unsigned)(p & 0xFFFFFFFFull);
            out[row * KSEL + rank] = vn;
            float* coor = out + VALS_TOTAL + ((size_t)row * KSEL + rank) * 2;
            coor[0] = (float)(idx >> 7);          // h = idx / 128
            coor[1] = (float)(idx & (WDIM - 1));  // w = idx % 128
        }
    }
}

extern "C" void kernel_launch(void* const* d_in, const int* in_sizes, int n_in,
                              void* d_out, int out_size, void* d_ws, size_t ws_size,
                              hipStream_t stream) {
    const float* x = (const float*)d_in[0];
    float* out = (float*)d_out;
    topk_rows<<<NROWS, 256, 0, stream>>>(x, out);
}